// Round 1
// baseline (1384.074 us; speedup 1.0000x reference)
//
#include <hip/hip_runtime.h>

// ---------------- constants ----------------
constexpr int S = 197;
constexpr int B = 64;
constexpr int E = 768;
constexpr int H = 12;
constexpr int D = 64;
constexpr int M = S * B;                  // 12608 rows, qkv GEMM order m = s*B+b
constexpr size_t SBE = (size_t)M * E;     // floats in one [*,768] buffer (9,682,944)

// ---------------- block reductions ----------------
__device__ __forceinline__ float bsum(float v, float* sm, int tid) {
#pragma unroll
  for (int off = 32; off > 0; off >>= 1) v += __shfl_down(v, off, 64);
  if ((tid & 63) == 0) sm[tid >> 6] = v;
  __syncthreads();
  float r = sm[0] + sm[1] + sm[2] + sm[3];
  __syncthreads();
  return r;
}
__device__ __forceinline__ float bmax(float v, float* sm, int tid) {
#pragma unroll
  for (int off = 32; off > 0; off >>= 1) v = fmaxf(v, __shfl_down(v, off, 64));
  if ((tid & 63) == 0) sm[tid >> 6] = v;
  __syncthreads();
  float r = fmaxf(fmaxf(sm[0], sm[1]), fmaxf(sm[2], sm[3]));
  __syncthreads();
  return r;
}

// ---------------- R[s,t] = rel[196+s] . rel[196+t] ----------------
__global__ __launch_bounds__(256) void mha_relR(const float* __restrict__ rel,
                                                float* __restrict__ Rb) {
  int idx = blockIdx.x * 256 + threadIdx.x;
  if (idx >= S * S) return;
  int s = idx / S, t = idx - s * S;
  const float* a = rel + (size_t)(S - 1 + s) * D;
  const float* b = rel + (size_t)(S - 1 + t) * D;
  float acc = 0.f;
#pragma unroll 8
  for (int d = 0; d < D; ++d) acc = fmaf(a[d], b[d], acc);
  Rb[idx] = acc;
}

// ---------------- QKV grouped GEMM + channel shuffle + head scatter + rel fold
// x row m = s*B+b is query[s,b,:] (contiguous). Pre-shuffle col p = g*288+i uses
// x slice [g*96, g*96+96) and qkv_w row p. Shuffled channel c' = i*8+g;
// which = c'/768, e = c'%768, h = e/64, d = e%64.
// qhat = 0.125*(y+b) + rel[196+s];  khat = (y+b) + rel[196+t];  v = y+b.
__global__ __launch_bounds__(256) void mha_qkv(const float* __restrict__ x,
                                               const float* __restrict__ w,
                                               const float* __restrict__ bias,
                                               const float* __restrict__ rel,
                                               float* __restrict__ qhat,
                                               float* __restrict__ khat,
                                               float* __restrict__ vbuf) {
  __shared__ float Xs[64][97];
  __shared__ float Ws[96][97];
  const int m0 = blockIdx.x * 64;
  const int n0 = blockIdx.y * 96;
  const int g = n0 / 288;
  const int tid = threadIdx.x;
  for (int idx = tid; idx < 64 * 96; idx += 256) {
    int m = idx / 96, k = idx - m * 96;
    int gm = m0 + m;
    Xs[m][k] = (gm < M) ? x[(size_t)gm * E + g * 96 + k] : 0.f;
  }
  for (int idx = tid; idx < 96 * 96; idx += 256) {
    int n = idx / 96, k = idx - n * 96;
    Ws[k][n] = w[(size_t)(n0 + n) * 96 + k];
  }
  __syncthreads();
  const int tx = tid & 15, ty = tid >> 4;
  float acc[4][6] = {};
  for (int k = 0; k < 96; ++k) {
    float a[4], bb[6];
#pragma unroll
    for (int r = 0; r < 4; ++r) a[r] = Xs[ty * 4 + r][k];
#pragma unroll
    for (int c = 0; c < 6; ++c) bb[c] = Ws[k][tx * 6 + c];
#pragma unroll
    for (int r = 0; r < 4; ++r)
#pragma unroll
      for (int c = 0; c < 6; ++c) acc[r][c] = fmaf(a[r], bb[c], acc[r][c]);
  }
#pragma unroll
  for (int r = 0; r < 4; ++r) {
    int m = m0 + ty * 4 + r;
    if (m >= M) continue;
    int s = m >> 6, b = m & 63;  // m = s*B + b, B=64
#pragma unroll
    for (int c = 0; c < 6; ++c) {
      int p = n0 + tx * 6 + c;
      float val = acc[r][c] + bias[p];
      int i = p - g * 288;
      int cp = i * 8 + g;
      int which = cp / 768;
      int e = cp - which * 768;
      int h = e >> 6, d = e & 63;
      size_t o = (((size_t)b * H + h) * S + s) * D + d;
      float rv = rel[(size_t)(S - 1 + s) * D + d];
      if (which == 0)      qhat[o] = 0.125f * val + rv;
      else if (which == 1) khat[o] = val + rv;
      else                 vbuf[o] = val;
    }
  }
}

// ---------------- attn logits: probs_chunk[bhl,s,t] = qhat.khat - R ------------
__global__ __launch_bounds__(256) void mha_attn(const float* __restrict__ qhat,
                                                const float* __restrict__ khat,
                                                const float* __restrict__ Rb,
                                                float* __restrict__ probs,
                                                int b0) {
  __shared__ float Qs[64][65];
  __shared__ float Ks[64][65];
  const int s0 = blockIdx.x * 64, t0 = blockIdx.y * 64;
  const int bhl = blockIdx.z;
  const size_t bh = (size_t)b0 * H + bhl;
  const float* q = qhat + bh * S * D;
  const float* kk = khat + bh * S * D;
  const int tid = threadIdx.x;
  for (int idx = tid; idx < 64 * 64; idx += 256) {
    int r = idx >> 6, d = idx & 63;
    Qs[r][d] = (s0 + r < S) ? q[(size_t)(s0 + r) * D + d] : 0.f;
    Ks[r][d] = (t0 + r < S) ? kk[(size_t)(t0 + r) * D + d] : 0.f;
  }
  __syncthreads();
  const int tx = tid & 15, ty = tid >> 4;
  float acc[4][4] = {};
  for (int d = 0; d < 64; ++d) {
    float a[4], bb[4];
#pragma unroll
    for (int r = 0; r < 4; ++r) a[r] = Qs[ty * 4 + r][d];
#pragma unroll
    for (int c = 0; c < 4; ++c) bb[c] = Ks[tx * 4 + c][d];
#pragma unroll
    for (int r = 0; r < 4; ++r)
#pragma unroll
      for (int c = 0; c < 4; ++c) acc[r][c] = fmaf(a[r], bb[c], acc[r][c]);
  }
#pragma unroll
  for (int r = 0; r < 4; ++r) {
#pragma unroll
    for (int c = 0; c < 4; ++c) {
      int s = s0 + ty * 4 + r, t = t0 + tx * 4 + c;
      if (s < S && t < S)
        probs[((size_t)bhl * S + s) * S + t] = acc[r][c] - Rb[s * S + t];
    }
  }
}

// ---------------- softmax rows + head-average into d_out -----------------------
__global__ __launch_bounds__(256) void mha_softmax(float* __restrict__ probs,
                                                   float* __restrict__ avg,
                                                   int b0) {
  __shared__ float sm[4];
  const int s = blockIdx.x;
  const int bl = blockIdx.y;
  const int b = b0 + bl;
  const int tid = threadIdx.x;
  float asum = 0.f;
  for (int h = 0; h < H; ++h) {
    float* row = probs + (((size_t)bl * H + h) * S + s) * S;
    float xv = (tid < S) ? row[tid] : -3.0e38f;
    float mx = bmax(xv, sm, tid);
    float e = (tid < S) ? __expf(xv - mx) : 0.f;
    float sum = bsum(e, sm, tid);
    float p = e / sum;
    if (tid < S) row[tid] = p;
    asum += p;
  }
  if (tid < S) avg[((size_t)b * S + s) * S + tid] = asum * (1.f / H);
}

// ---------------- PV: context[b,s, h*64+d] = sum_t P[s,t] * V[t,d] -------------
__global__ __launch_bounds__(256) void mha_pv(const float* __restrict__ probs,
                                              const float* __restrict__ vbuf,
                                              float* __restrict__ context,
                                              int b0) {
  __shared__ float Ps[64][65];
  __shared__ float Vs[64][65];
  const int s0 = blockIdx.x * 64;
  const int bhl = blockIdx.y;
  const int bl = bhl / H, h = bhl - bl * H;
  const int b = b0 + bl;
  const size_t bh = (size_t)b * H + h;
  const int tid = threadIdx.x;
  const int tx = tid & 15, ty = tid >> 4;
  float acc[4][4] = {};
  for (int t0 = 0; t0 < S; t0 += 64) {
    for (int idx = tid; idx < 64 * 64; idx += 256) {
      int r = idx >> 6, c = idx & 63;
      Ps[r][c] = (s0 + r < S && t0 + c < S)
                     ? probs[((size_t)bhl * S + s0 + r) * S + t0 + c] : 0.f;
      Vs[r][c] = (t0 + r < S) ? vbuf[(bh * S + t0 + r) * D + c] : 0.f;
    }
    __syncthreads();
    for (int k = 0; k < 64; ++k) {
      float a[4], bb[4];
#pragma unroll
      for (int r = 0; r < 4; ++r) a[r] = Ps[ty * 4 + r][k];
#pragma unroll
      for (int c = 0; c < 4; ++c) bb[c] = Vs[k][tx * 4 + c];
#pragma unroll
      for (int r = 0; r < 4; ++r)
#pragma unroll
        for (int c = 0; c < 4; ++c) acc[r][c] = fmaf(a[r], bb[c], acc[r][c]);
    }
    __syncthreads();
  }
#pragma unroll
  for (int r = 0; r < 4; ++r) {
    int s = s0 + ty * 4 + r;
    if (s >= S) continue;
#pragma unroll
    for (int c = 0; c < 4; ++c) {
      int d = tx * 4 + c;
      context[((size_t)b * S + s) * E + h * 64 + d] = acc[r][c];
    }
  }
}

// ---------------- LayerNorm over E -------------------------------------------
__global__ __launch_bounds__(256) void mha_ln(const float* __restrict__ x,
                                              const float* __restrict__ g,
                                              const float* __restrict__ bb,
                                              float* __restrict__ y) {
  __shared__ float sm[4];
  const size_t r = blockIdx.x;
  const float* xr = x + r * E;
  const int tid = threadIdx.x;
  float s1 = 0.f, s2 = 0.f;
  for (int i = tid; i < E; i += 256) {
    float v = xr[i];
    s1 += v;
    s2 += v * v;
  }
  s1 = bsum(s1, sm, tid);
  s2 = bsum(s2, sm, tid);
  float mu = s1 * (1.f / E);
  float var = s2 * (1.f / E) - mu * mu;
  float inv = rsqrtf(var + 1e-5f);
  float* yr = y + r * E;
  for (int i = tid; i < E; i += 256) yr[i] = (xr[i] - mu) * inv * g[i] + bb[i];
}

// ---------------- fc1 (768->96) + tanh-gelu ------------------------------------
__global__ __launch_bounds__(256) void mha_fc1(const float* __restrict__ ln,
                                               const float* __restrict__ w,
                                               const float* __restrict__ bias,
                                               float* __restrict__ h1) {
  __shared__ float Ls[64][33];
  __shared__ float Ws[32][97];
  const int m0 = blockIdx.x * 64;
  const int tid = threadIdx.x;
  const int tx = tid & 15, ty = tid >> 4;
  float acc[4][6] = {};
  for (int k0 = 0; k0 < E; k0 += 32) {
    for (int idx = tid; idx < 64 * 32; idx += 256) {
      int m = idx >> 5, k = idx & 31;
      Ls[m][k] = (m0 + m < M) ? ln[(size_t)(m0 + m) * E + k0 + k] : 0.f;
    }
    for (int idx = tid; idx < 32 * 96; idx += 256) {
      int k = idx / 96, n = idx - k * 96;
      Ws[k][n] = w[(size_t)(k0 + k) * 96 + n];
    }
    __syncthreads();
    for (int k = 0; k < 32; ++k) {
      float a[4], bb[6];
#pragma unroll
      for (int r = 0; r < 4; ++r) a[r] = Ls[ty * 4 + r][k];
#pragma unroll
      for (int c = 0; c < 6; ++c) bb[c] = Ws[k][tx * 6 + c];
#pragma unroll
      for (int r = 0; r < 4; ++r)
#pragma unroll
        for (int c = 0; c < 6; ++c) acc[r][c] = fmaf(a[r], bb[c], acc[r][c]);
    }
    __syncthreads();
  }
#pragma unroll
  for (int r = 0; r < 4; ++r) {
    int m = m0 + ty * 4 + r;
    if (m >= M) continue;
#pragma unroll
    for (int c = 0; c < 6; ++c) {
      int n = tx * 6 + c;
      float u = acc[r][c] + bias[n];
      float gl = 0.5f * u * (1.f + tanhf(0.7978845608028654f * (u + 0.044715f * u * u * u)));
      h1[(size_t)m * 96 + n] = gl;
    }
  }
}

// ---------------- fc2 (96->768) + sigmoid, scale context -----------------------
__global__ __launch_bounds__(256) void mha_fc2(const float* __restrict__ h1,
                                               const float* __restrict__ w,
                                               const float* __restrict__ bias,
                                               const float* __restrict__ context,
                                               float* __restrict__ attn2) {
  __shared__ float Hs[64][97];
  __shared__ float Ws[96][65];
  const int m0 = blockIdx.x * 64;
  const int n0 = blockIdx.y * 64;
  const int tid = threadIdx.x;
  for (int idx = tid; idx < 64 * 96; idx += 256) {
    int m = idx / 96, k = idx - m * 96;
    Hs[m][k] = (m0 + m < M) ? h1[(size_t)(m0 + m) * 96 + k] : 0.f;
  }
  for (int idx = tid; idx < 96 * 64; idx += 256) {
    int k = idx >> 6, n = idx & 63;
    Ws[k][n] = w[(size_t)k * E + n0 + n];
  }
  __syncthreads();
  const int tx = tid & 15, ty = tid >> 4;
  float acc[4][4] = {};
  for (int k = 0; k < 96; ++k) {
    float a[4], bb[4];
#pragma unroll
    for (int r = 0; r < 4; ++r) a[r] = Hs[ty * 4 + r][k];
#pragma unroll
    for (int c = 0; c < 4; ++c) bb[c] = Ws[k][tx * 4 + c];
#pragma unroll
    for (int r = 0; r < 4; ++r)
#pragma unroll
      for (int c = 0; c < 4; ++c) acc[r][c] = fmaf(a[r], bb[c], acc[r][c]);
  }
#pragma unroll
  for (int r = 0; r < 4; ++r) {
    int m = m0 + ty * 4 + r;
    if (m >= M) continue;
#pragma unroll
    for (int c = 0; c < 4; ++c) {
      int e = n0 + tx * 4 + c;
      float val = acc[r][c] + bias[e];
      float sg = 1.f / (1.f + __expf(-val));
      attn2[(size_t)m * E + e] = context[(size_t)m * E + e] * sg;
    }
  }
}

// ---------------- grouped out projection + bias + transpose to [S,B,E] ---------
__global__ __launch_bounds__(256) void mha_out(const float* __restrict__ attn2,
                                               const float* __restrict__ w,
                                               const float* __restrict__ bias,
                                               float* __restrict__ outp) {
  __shared__ float As[64][97];
  __shared__ float Ws[96][97];
  const int m0 = blockIdx.x * 64;
  const int g = blockIdx.y;
  const int n0 = g * 96;
  const int tid = threadIdx.x;
  for (int idx = tid; idx < 64 * 96; idx += 256) {
    int m = idx / 96, j = idx - m * 96;
    As[m][j] = (m0 + m < M) ? attn2[(size_t)(m0 + m) * E + g * 96 + j] : 0.f;
  }
  for (int idx = tid; idx < 96 * 96; idx += 256) {
    int n = idx / 96, j = idx - n * 96;
    Ws[n][j] = w[(size_t)(n0 + n) * 96 + j];
  }
  __syncthreads();
  const int tx = tid & 15, ty = tid >> 4;
  float acc[4][6] = {};
  for (int j = 0; j < 96; ++j) {
    float a[4], bb[6];
#pragma unroll
    for (int r = 0; r < 4; ++r) a[r] = As[ty * 4 + r][j];
#pragma unroll
    for (int c = 0; c < 6; ++c) bb[c] = Ws[tx * 6 + c][j];
#pragma unroll
    for (int r = 0; r < 4; ++r)
#pragma unroll
      for (int c = 0; c < 6; ++c) acc[r][c] = fmaf(a[r], bb[c], acc[r][c]);
  }
#pragma unroll
  for (int r = 0; r < 4; ++r) {
    int m = m0 + ty * 4 + r;
    if (m >= M) continue;
    int b = m / S, s = m - b * S;  // rows here are r = b*S + s
#pragma unroll
    for (int c = 0; c < 6; ++c) {
      int p = n0 + tx * 6 + c;
      outp[((size_t)s * B + b) * E + p] = acc[r][c] + bias[p];
    }
  }
}

// ---------------- host launcher ------------------------------------------------
extern "C" void kernel_launch(void* const* d_in, const int* in_sizes, int n_in,
                              void* d_out, int out_size, void* d_ws, size_t ws_size,
                              hipStream_t stream) {
  const float* query = (const float*)d_in[0];
  const float* qkv_w = (const float*)d_in[3];
  const float* qkv_b = (const float*)d_in[4];
  const float* out_w = (const float*)d_in[5];
  const float* out_b = (const float*)d_in[6];
  const float* rel   = (const float*)d_in[7];
  const float* ln_g  = (const float*)d_in[8];
  const float* ln_b  = (const float*)d_in[9];
  const float* fc1_w = (const float*)d_in[10];
  const float* fc1_b = (const float*)d_in[11];
  const float* fc2_w = (const float*)d_in[12];
  const float* fc2_b = (const float*)d_in[13];

  float* ws = (float*)d_ws;
  float* qhat    = ws;                 // [B,H,S,D] = SBE floats
  float* khat    = ws + SBE;           // [B,H,S,D]
  float* vbuf    = ws + 2 * SBE;       // [B,H,S,D]
  float* context = ws + 3 * SBE;       // rows b*S+s, [.,768]
  float* Rbuf    = ws + 4 * SBE;       // 197*197
  float* probs   = ws + 4 * SBE + 38816;  // chunked [bc,H,S,S]
  float* lnbuf = qhat;   // reuse after attention
  float* h1    = khat;   // reuse
  float* attn2 = vbuf;   // reuse
  float* outp  = (float*)d_out;
  float* avgp  = outp + SBE;

  size_t used = 4 * SBE + 38816;
  size_t availf = (ws_size / 4 > used) ? (ws_size / 4 - used) : 0;
  size_t perb = (size_t)H * S * S;
  int Bc = (int)(availf / perb);
  if (Bc < 1) Bc = 1;
  if (Bc > B) Bc = B;

  mha_relR<<<(S * S + 255) / 256, 256, 0, stream>>>(rel, Rbuf);
  mha_qkv<<<dim3(M / 64, 24), 256, 0, stream>>>(query, qkv_w, qkv_b, rel, qhat, khat, vbuf);
  for (int b0 = 0; b0 < B; b0 += Bc) {
    int bc = (B - b0 < Bc) ? (B - b0) : Bc;
    mha_attn<<<dim3(4, 4, bc * H), 256, 0, stream>>>(qhat, khat, Rbuf, probs, b0);
    mha_softmax<<<dim3(S, bc), 256, 0, stream>>>(probs, avgp, b0);
    mha_pv<<<dim3(4, bc * H), 256, 0, stream>>>(probs, vbuf, context, b0);
  }
  mha_ln<<<M, 256, 0, stream>>>(context, ln_g, ln_b, lnbuf);
  mha_fc1<<<M / 64, 256, 0, stream>>>(lnbuf, fc1_w, fc1_b, h1);
  mha_fc2<<<dim3(M / 64, 12), 256, 0, stream>>>(h1, fc2_w, fc2_b, context, attn2);
  mha_out<<<dim3(M / 64, 8), 256, 0, stream>>>(attn2, out_w, out_b, outp);
}